// Round 14
// baseline (1067.027 us; speedup 1.0000x reference)
//
#include <hip/hip_runtime.h>
#include <math.h>

#define T_SEQ 1024
#define LH 125      // lstm hidden
#define G4 500      // 4*L gates

typedef _Float16 v8h __attribute__((ext_vector_type(8)));
typedef float f32x4 __attribute__((ext_vector_type(4)));

__device__ __forceinline__ float ftanh(float x) {
    float e = __builtin_amdgcn_exp2f(x * -2.8853900817779268f);
    return 2.f * __builtin_amdgcn_rcpf(1.f + e) - 1.f;
}

// pack 8 f32 weights -> 8 f16 (zero for k >= LH), compile-time element indices
__device__ __forceinline__ v8h packa8(const float* __restrict__ rowp, int kbase) {
    v8h r;
#define PA(j) { int k = kbase + (j); r[j] = (k < LH) ? (_Float16)rowp[k] : (_Float16)0.f; }
    PA(0) PA(1) PA(2) PA(3) PA(4) PA(5) PA(6) PA(7)
#undef PA
    return r;
}

// ---------------- layer-0 input projection, embedding fused, 4 timesteps/block
// Stores pre interleaved: pre[t][unit][gate] (gate: 0=i,1=f,2=g,3=o)
__global__ void k_preproj0(const int* __restrict__ wid, const int* __restrict__ pid,
                           const float* __restrict__ W_emb, const float* __restrict__ P_emb,
                           const float* __restrict__ Wf, const float* __restrict__ bf,
                           const float* __restrict__ Wb, const float* __restrict__ bb,
                           float* __restrict__ pf, float* __restrict__ pb) {
    __shared__ float xs[4][128];
    const int t0 = blockIdx.x * 4;
    const int tid = threadIdx.x;   // 512
    for (int tt = 0; tt < 4; ++tt) {
        int t = t0 + tt;
        for (int k = tid; k < 125; k += 512)
            xs[tt][k] = (k < 100) ? W_emb[wid[t] * 100 + k] : P_emb[pid[t] * 25 + (k - 100)];
    }
    __syncthreads();
    const int j = tid;
    if (j < G4) {
        const float* wf = Wf + j * 125;
        const float* wb = Wb + j * 125;
        float af0 = bf[j], af1 = af0, af2 = af0, af3 = af0;
        float ab0 = bb[j], ab1 = ab0, ab2 = ab0, ab3 = ab0;
        #pragma unroll 5
        for (int k = 0; k < 125; ++k) {
            float wfk = wf[k], wbk = wb[k];
            af0 += wfk * xs[0][k]; af1 += wfk * xs[1][k];
            af2 += wfk * xs[2][k]; af3 += wfk * xs[3][k];
            ab0 += wbk * xs[0][k]; ab1 += wbk * xs[1][k];
            ab2 += wbk * xs[2][k]; ab3 += wbk * xs[3][k];
        }
        int g = j / 125, u = j - g * 125;
        int off = u * 4 + g;
        pf[(t0 + 0) * G4 + off] = af0; pf[(t0 + 1) * G4 + off] = af1;
        pf[(t0 + 2) * G4 + off] = af2; pf[(t0 + 3) * G4 + off] = af3;
        pb[(t0 + 0) * G4 + off] = ab0; pb[(t0 + 1) * G4 + off] = ab1;
        pb[(t0 + 2) * G4 + off] = ab2; pb[(t0 + 3) * G4 + off] = ab3;
    }
}

// ---------------- layer-1 input projection (input = h1, K=250), interleaved store
__global__ void k_preproj1(const float* __restrict__ h1,
                           const float* __restrict__ Wf, const float* __restrict__ bf,
                           const float* __restrict__ Wb, const float* __restrict__ bb,
                           float* __restrict__ pf, float* __restrict__ pb) {
    __shared__ float xs[4][256];
    const int t0 = blockIdx.x * 4;
    const int tid = threadIdx.x;   // 512
    for (int tt = 0; tt < 4; ++tt) {
        int t = t0 + tt;
        for (int k = tid; k < 250; k += 512) xs[tt][k] = h1[t * 250 + k];
    }
    __syncthreads();
    const int j = tid;
    if (j < G4) {
        const float* wf = Wf + j * 250;
        const float* wb = Wb + j * 250;
        float af0 = bf[j], af1 = af0, af2 = af0, af3 = af0;
        float ab0 = bb[j], ab1 = ab0, ab2 = ab0, ab3 = ab0;
        #pragma unroll 5
        for (int k = 0; k < 250; ++k) {
            float wfk = wf[k], wbk = wb[k];
            af0 += wfk * xs[0][k]; af1 += wfk * xs[1][k];
            af2 += wfk * xs[2][k]; af3 += wfk * xs[3][k];
            ab0 += wbk * xs[0][k]; ab1 += wbk * xs[1][k];
            ab2 += wbk * xs[2][k]; ab3 += wbk * xs[3][k];
        }
        int g = j / 125, u = j - g * 125;
        int off = u * 4 + g;
        pf[(t0 + 0) * G4 + off] = af0; pf[(t0 + 1) * G4 + off] = af1;
        pf[(t0 + 2) * G4 + off] = af2; pf[(t0 + 3) * G4 + off] = af3;
        pb[(t0 + 0) * G4 + off] = ab0; pb[(t0 + 1) * G4 + off] = ab1;
        pb[(t0 + 2) * G4 + off] = ab2; pb[(t0 + 3) * G4 + off] = ab3;
    }
}

// ---------------- MFMA LSTM scan, one 512-thread block per direction.
// r9 structure + trans de-dup: replica r = (lane>>2)&3 computes ONLY gate r's
// nonlinearity (2 trans); ds_swizzle xor {4,8,12} redistributes the 4 gates to all
// replicas; 12 cndmask reassemble {i,f,g,o}; c/tanh per-lane. Per-lane trans 10 -> 4.
__global__ void __attribute__((amdgpu_flat_work_group_size(512, 512)))
__attribute__((amdgpu_waves_per_eu(2, 2)))
k_scan(const float* __restrict__ pf, const float* __restrict__ Wf,
       const float* __restrict__ pb, const float* __restrict__ Wb,
       float* __restrict__ hout) {
    const int dir = blockIdx.x;
    const float* __restrict__ pre = dir ? pb : pf;   // [T][125][4]
    const float* __restrict__ Whh = dir ? Wb : Wf;   // [4][125][125] original
    const int col0 = dir ? 0 : 125;

    __shared__ __align__(32) _Float16 h_lds[2 * 128];   // 2 buffers x 128 halves

    const int t9   = threadIdx.x;
    const int w    = t9 >> 6;        // wave 0..7
    const int lane = t9 & 63;
    const int lane15 = lane & 15;
    const int hi16   = lane >> 4;    // 0..3
    const bool mb0 = (lane & 1) != 0;
    const bool mb1 = (lane & 2) != 0;
    const bool b2  = (lane & 4) != 0;   // replica bit 0
    const bool b3  = (lane & 8) != 0;   // replica bit 1
    const int r_gate = (lane >> 2) & 3; // gate this replica computes

    const int uo    = 4 * (lane & 3) + hi16;   // unit-in-wave this lane owns
    const int u_raw = 16 * w + uo;
    const bool valid = (u_raw < LH);
    const int u = valid ? u_raw : (LH - 1);
    const bool writer = ((lane & 12) == 0) && valid;

    // own-gate nonlinearity constants: sigmoid for r in {0,1,3}, tanh for r==2
    const bool is_sig = (r_gate != 2);
    const float Ac  = is_sig ? 1.f : 2.f;
    const float Bc2 = is_sig ? -1.4426950408889634f : -2.8853900817779268f;
    const float Cc  = is_sig ? 0.f : -1.f;

    // ---- A fragments: 4 M-tiles x 4 K-tiles, row' = 64w + 16m + lane15 (clamped),
    // orig row = (row'&3)*125 + (row'>>2); k = kt*32 + hi16*8 + j.
#define LROW(m) int ro##m; { int rp = 64 * w + 16 * m + lane15; if (rp > 499) rp = 499; \
                             ro##m = (rp & 3) * 125 + (rp >> 2); }
    LROW(0) LROW(1) LROW(2) LROW(3)
#undef LROW
#define LA(m) v8h a##m##0 = packa8(Whh + ro##m * LH, hi16 * 8); \
              v8h a##m##1 = packa8(Whh + ro##m * LH, 32 + hi16 * 8); \
              v8h a##m##2 = packa8(Whh + ro##m * LH, 64 + hi16 * 8); \
              v8h a##m##3 = packa8(Whh + ro##m * LH, 96 + hi16 * 8);
    LA(0) LA(1) LA(2) LA(3)
#undef LA

    for (int q = t9; q < 2 * 128; q += 512) h_lds[q] = (_Float16)0.f;
    float c = 0.f;
    __syncthreads();

    // walking int offsets; per-lane pre element = [t][u][r_gate]
    const int pstride = dir ? -G4 : G4;
    int poff = (dir ? (T_SEQ - 1) * G4 : 0) + u * 4 + r_gate;
    const int gstride = dir ? -250 : 250;
    int goff = (dir ? (T_SEQ - 1) * 250 : 0) + col0 + u;
    float pv = pre[poff];
    poff += pstride;

    const int bbase = hi16 * 8;   // halves offset within a K-tile row

#define SCAN_STEP(CUR, NXT) { \
    float pvn = pre[poff]; poff += pstride; \
    const _Float16* hb = &h_lds[(CUR) * 128 + bbase]; \
    v8h bb0 = *reinterpret_cast<const v8h*>(hb); \
    v8h bb1 = *reinterpret_cast<const v8h*>(hb + 32); \
    v8h bb2 = *reinterpret_cast<const v8h*>(hb + 64); \
    v8h bb3 = *reinterpret_cast<const v8h*>(hb + 96); \
    f32x4 z = {0.f, 0.f, 0.f, 0.f}; \
    f32x4 acc0 = __builtin_amdgcn_mfma_f32_16x16x32_f16(a00, bb0, z, 0, 0, 0); \
    acc0 = __builtin_amdgcn_mfma_f32_16x16x32_f16(a01, bb1, acc0, 0, 0, 0); \
    acc0 = __builtin_amdgcn_mfma_f32_16x16x32_f16(a02, bb2, acc0, 0, 0, 0); \
    acc0 = __builtin_amdgcn_mfma_f32_16x16x32_f16(a03, bb3, acc0, 0, 0, 0); \
    f32x4 acc1 = __builtin_amdgcn_mfma_f32_16x16x32_f16(a10, bb0, z, 0, 0, 0); \
    acc1 = __builtin_amdgcn_mfma_f32_16x16x32_f16(a11, bb1, acc1, 0, 0, 0); \
    acc1 = __builtin_amdgcn_mfma_f32_16x16x32_f16(a12, bb2, acc1, 0, 0, 0); \
    acc1 = __builtin_amdgcn_mfma_f32_16x16x32_f16(a13, bb3, acc1, 0, 0, 0); \
    f32x4 acc2 = __builtin_amdgcn_mfma_f32_16x16x32_f16(a20, bb0, z, 0, 0, 0); \
    acc2 = __builtin_amdgcn_mfma_f32_16x16x32_f16(a21, bb1, acc2, 0, 0, 0); \
    acc2 = __builtin_amdgcn_mfma_f32_16x16x32_f16(a22, bb2, acc2, 0, 0, 0); \
    acc2 = __builtin_amdgcn_mfma_f32_16x16x32_f16(a23, bb3, acc2, 0, 0, 0); \
    f32x4 acc3 = __builtin_amdgcn_mfma_f32_16x16x32_f16(a30, bb0, z, 0, 0, 0); \
    acc3 = __builtin_amdgcn_mfma_f32_16x16x32_f16(a31, bb1, acc3, 0, 0, 0); \
    acc3 = __builtin_amdgcn_mfma_f32_16x16x32_f16(a32, bb2, acc3, 0, 0, 0); \
    acc3 = __builtin_amdgcn_mfma_f32_16x16x32_f16(a33, bb3, acc3, 0, 0, 0); \
    /* select own-gate raw sum: reg r_gate of owned m-tile (compile-time indices) */ \
    float v0 = b3 ? (b2 ? acc0[3] : acc0[2]) : (b2 ? acc0[1] : acc0[0]); \
    float v1 = b3 ? (b2 ? acc1[3] : acc1[2]) : (b2 ? acc1[1] : acc1[0]); \
    float v2 = b3 ? (b2 ? acc2[3] : acc2[2]) : (b2 ? acc2[1] : acc2[0]); \
    float v3 = b3 ? (b2 ? acc3[3] : acc3[2]) : (b2 ? acc3[1] : acc3[0]); \
    float x01 = mb0 ? v1 : v0; \
    float x23 = mb0 ? v3 : v2; \
    float own_raw = mb1 ? x23 : x01; \
    /* one nonlinearity per lane (gate r_gate) */ \
    float gv = Ac * __builtin_amdgcn_rcpf( \
                   1.f + __builtin_amdgcn_exp2f(Bc2 * (own_raw + pv))) + Cc; \
    /* redistribute gates across the 4 replicas: s4 = gate r^1, s8 = r^2, s12 = r^3 */ \
    float s4  = __int_as_float(__builtin_amdgcn_ds_swizzle(__float_as_int(gv), 0x101F)); \
    float s8  = __int_as_float(__builtin_amdgcn_ds_swizzle(__float_as_int(gv), 0x201F)); \
    float s12 = __int_as_float(__builtin_amdgcn_ds_swizzle(__float_as_int(gv), 0x301F)); \
    float giv = b3 ? (b2 ? s12 : s8) : (b2 ? s4 : gv); \
    float gfv = b3 ? (b2 ? s8 : s12) : (b2 ? gv : s4); \
    float ggv = b3 ? (b2 ? s4 : gv) : (b2 ? s12 : s8); \
    float gov = b3 ? (b2 ? gv : s4) : (b2 ? s8 : s12); \
    c = gfv * c + giv * ggv; \
    float hnew = gov * ftanh(c); \
    if (writer) { \
        h_lds[(NXT) * 128 + u] = (_Float16)hnew; \
        hout[goff] = hnew; \
    } \
    goff += gstride; \
    __syncthreads(); \
    pv = pvn; \
}

    for (int s2 = 0; s2 < T_SEQ; s2 += 2) {
        SCAN_STEP(0, 1)
        SCAN_STEP(1, 0)
    }
#undef SCAN_STEP
}

// ---------------- head' = h2 @ FOH + bias ; mod = h2 @ FOM
__global__ void k_headmod(const float* __restrict__ h2,
                          const float* __restrict__ FOH, const float* __restrict__ FOM,
                          const float* __restrict__ bias,
                          float* __restrict__ headp, float* __restrict__ modv) {
    __shared__ float hs[250];
    int t = blockIdx.x, tid = threadIdx.x;   // block 256
    for (int k = tid; k < 250; k += 256) hs[k] = h2[t * 250 + k];
    __syncthreads();
    if (tid < 100) {
        float a = 0.f;
        #pragma unroll 5
        for (int k = 0; k < 250; ++k) a += hs[k] * FOH[k * 100 + tid];
        headp[t * 100 + tid] = a + bias[tid];
    } else if (tid >= 128 && tid < 228) {
        int h = tid - 128;
        float a = 0.f;
        #pragma unroll 5
        for (int k = 0; k < 250; ++k) a += hs[k] * FOM[k * 100 + h];
        modv[t * 100 + h] = a;
    }
}

// ---------------- scores[i][j] = sum_h tanh(head'[i][h] + mod[j][h]) * outW[h]
__global__ void k_score(const float* __restrict__ headp, const float* __restrict__ modv,
                        const float* __restrict__ outw, float* __restrict__ out) {
    __shared__ float hh[16][100];
    __shared__ float mm[16][100];
    __shared__ float ow[100];
    const int bi = blockIdx.y, bj = blockIdx.x;
    const int tx = threadIdx.x, ty = threadIdx.y;   // 16x16
    const int tid = ty * 16 + tx;
    for (int q = tid; q < 1600; q += 256) {
        int r = q / 100, cidx = q % 100;
        hh[r][cidx] = headp[(bi * 16 + r) * 100 + cidx];
        mm[r][cidx] = modv[(bj * 16 + r) * 100 + cidx];
    }
    if (tid < 100) ow[tid] = outw[tid];
    __syncthreads();
    float acc = 0.f;
    #pragma unroll 4
    for (int h = 0; h < 100; ++h) {
        float e = __builtin_amdgcn_exp2f((hh[ty][h] + mm[tx][h]) * -2.8853900817779268f);
        acc += (2.f * __builtin_amdgcn_rcpf(1.f + e) - 1.f) * ow[h];
    }
    out[(bi * 16 + ty) * 1024 + (bj * 16 + tx)] = acc;
}

extern "C" void kernel_launch(void* const* d_in, const int* in_sizes, int n_in,
                              void* d_out, int out_size, void* d_ws, size_t ws_size,
                              hipStream_t stream) {
    const int*   wid    = (const int*)d_in[0];
    const int*   pid    = (const int*)d_in[1];
    const float* W_emb  = (const float*)d_in[2];
    const float* P_emb  = (const float*)d_in[3];
    const float* Wih_f0 = (const float*)d_in[4];
    const float* Whh_f0 = (const float*)d_in[5];
    const float* b_f0   = (const float*)d_in[6];
    const float* Wih_b0 = (const float*)d_in[7];
    const float* Whh_b0 = (const float*)d_in[8];
    const float* b_b0   = (const float*)d_in[9];
    const float* Wih_f1 = (const float*)d_in[10];
    const float* Whh_f1 = (const float*)d_in[11];
    const float* b_f1   = (const float*)d_in[12];
    const float* Wih_b1 = (const float*)d_in[13];
    const float* Whh_b1 = (const float*)d_in[14];
    const float* b_b1   = (const float*)d_in[15];
    const float* FOH    = (const float*)d_in[16];
    const float* FOM    = (const float*)d_in[17];
    const float* hidB   = (const float*)d_in[18];
    const float* outW   = (const float*)d_in[19];
    float* out = (float*)d_out;
    float* ws  = (float*)d_ws;

    float* pf    = ws;                  // 1024*500 (interleaved [t][u][gate])
    float* pb    = pf    + 512000;
    float* h1    = pb    + 512000;      // 1024*250
    float* h2    = h1    + 256000;
    float* headp = h2    + 256000;      // 1024*100
    float* modv  = headp + 102400;

    k_preproj0<<<256, 512, 0, stream>>>(wid, pid, W_emb, P_emb,
                                        Wih_f0, b_f0, Wih_b0, b_b0, pf, pb);
    k_scan<<<2, 512, 0, stream>>>(pf, Whh_f0, pb, Whh_b0, h1);

    k_preproj1<<<256, 512, 0, stream>>>(h1, Wih_f1, b_f1, Wih_b1, b_b1, pf, pb);
    k_scan<<<2, 512, 0, stream>>>(pf, Whh_f1, pb, Whh_b1, h2);

    k_headmod<<<T_SEQ, 256, 0, stream>>>(h2, FOH, FOM, hidB, headp, modv);
    dim3 gs(64, 64), bs(16, 16);
    k_score<<<gs, bs, 0, stream>>>(headp, modv, outW, out);
}

// Round 15
// 1010.848 us; speedup vs baseline: 1.0556x; 1.0556x over previous
//
#include <hip/hip_runtime.h>
#include <math.h>

#define T_SEQ 1024
#define LH 125      // lstm hidden
#define G4 500      // 4*L gates

typedef _Float16 v8h __attribute__((ext_vector_type(8)));
typedef float f32x4 __attribute__((ext_vector_type(4)));

__device__ __forceinline__ float fsig(float x) {
    return __builtin_amdgcn_rcpf(1.f + __builtin_amdgcn_exp2f(x * -1.4426950408889634f));
}
__device__ __forceinline__ float ftanh(float x) {
    float e = __builtin_amdgcn_exp2f(x * -2.8853900817779268f);
    return 2.f * __builtin_amdgcn_rcpf(1.f + e) - 1.f;
}

// pack 8 f32 weights -> 8 f16 (zero for k >= LH), compile-time element indices
__device__ __forceinline__ v8h packa8(const float* __restrict__ rowp, int kbase) {
    v8h r;
#define PA(j) { int k = kbase + (j); r[j] = (k < LH) ? (_Float16)rowp[k] : (_Float16)0.f; }
    PA(0) PA(1) PA(2) PA(3) PA(4) PA(5) PA(6) PA(7)
#undef PA
    return r;
}

// ---------------- layer-0 input projection, embedding fused, 4 timesteps/block
// Stores pre interleaved: pre[t][unit][gate] (gate: 0=i,1=f,2=g,3=o)
__global__ void k_preproj0(const int* __restrict__ wid, const int* __restrict__ pid,
                           const float* __restrict__ W_emb, const float* __restrict__ P_emb,
                           const float* __restrict__ Wf, const float* __restrict__ bf,
                           const float* __restrict__ Wb, const float* __restrict__ bb,
                           float* __restrict__ pf, float* __restrict__ pb) {
    __shared__ float xs[4][128];
    const int t0 = blockIdx.x * 4;
    const int tid = threadIdx.x;   // 512
    for (int tt = 0; tt < 4; ++tt) {
        int t = t0 + tt;
        for (int k = tid; k < 125; k += 512)
            xs[tt][k] = (k < 100) ? W_emb[wid[t] * 100 + k] : P_emb[pid[t] * 25 + (k - 100)];
    }
    __syncthreads();
    const int j = tid;
    if (j < G4) {
        const float* wf = Wf + j * 125;
        const float* wb = Wb + j * 125;
        float af0 = bf[j], af1 = af0, af2 = af0, af3 = af0;
        float ab0 = bb[j], ab1 = ab0, ab2 = ab0, ab3 = ab0;
        #pragma unroll 5
        for (int k = 0; k < 125; ++k) {
            float wfk = wf[k], wbk = wb[k];
            af0 += wfk * xs[0][k]; af1 += wfk * xs[1][k];
            af2 += wfk * xs[2][k]; af3 += wfk * xs[3][k];
            ab0 += wbk * xs[0][k]; ab1 += wbk * xs[1][k];
            ab2 += wbk * xs[2][k]; ab3 += wbk * xs[3][k];
        }
        int g = j / 125, u = j - g * 125;
        int off = u * 4 + g;
        pf[(t0 + 0) * G4 + off] = af0; pf[(t0 + 1) * G4 + off] = af1;
        pf[(t0 + 2) * G4 + off] = af2; pf[(t0 + 3) * G4 + off] = af3;
        pb[(t0 + 0) * G4 + off] = ab0; pb[(t0 + 1) * G4 + off] = ab1;
        pb[(t0 + 2) * G4 + off] = ab2; pb[(t0 + 3) * G4 + off] = ab3;
    }
}

// ---------------- layer-1 input projection (input = h1, K=250), interleaved store
__global__ void k_preproj1(const float* __restrict__ h1,
                           const float* __restrict__ Wf, const float* __restrict__ bf,
                           const float* __restrict__ Wb, const float* __restrict__ bb,
                           float* __restrict__ pf, float* __restrict__ pb) {
    __shared__ float xs[4][256];
    const int t0 = blockIdx.x * 4;
    const int tid = threadIdx.x;   // 512
    for (int tt = 0; tt < 4; ++tt) {
        int t = t0 + tt;
        for (int k = tid; k < 250; k += 512) xs[tt][k] = h1[t * 250 + k];
    }
    __syncthreads();
    const int j = tid;
    if (j < G4) {
        const float* wf = Wf + j * 250;
        const float* wb = Wb + j * 250;
        float af0 = bf[j], af1 = af0, af2 = af0, af3 = af0;
        float ab0 = bb[j], ab1 = ab0, ab2 = ab0, ab3 = ab0;
        #pragma unroll 5
        for (int k = 0; k < 250; ++k) {
            float wfk = wf[k], wbk = wb[k];
            af0 += wfk * xs[0][k]; af1 += wfk * xs[1][k];
            af2 += wfk * xs[2][k]; af3 += wfk * xs[3][k];
            ab0 += wbk * xs[0][k]; ab1 += wbk * xs[1][k];
            ab2 += wbk * xs[2][k]; ab3 += wbk * xs[3][k];
        }
        int g = j / 125, u = j - g * 125;
        int off = u * 4 + g;
        pf[(t0 + 0) * G4 + off] = af0; pf[(t0 + 1) * G4 + off] = af1;
        pf[(t0 + 2) * G4 + off] = af2; pf[(t0 + 3) * G4 + off] = af3;
        pb[(t0 + 0) * G4 + off] = ab0; pb[(t0 + 1) * G4 + off] = ab1;
        pb[(t0 + 2) * G4 + off] = ab2; pb[(t0 + 3) * G4 + off] = ab3;
    }
}

// ---------------- MFMA LSTM scan (known-best r9/r13), one 512-thread block per dir.
// Wave w owns rows' [64w,64w+64) (row' = 4*unit+gate). 4 M-tiles x 4 chained K-tiles
// of mfma_f32_16x16x32_f16; B = h broadcast. C layout: reg r of tile m = gate r of
// unit 16w+4m+hi16. Tail fully in-lane; one barrier/step. 2 waves/SIMD cover each
// other's latency. Measured slower alternatives: prefetch-into-C (r10), 1-wave/SIMD
// (r12), ds_swizzle trans de-dup (r14) -- the tail is chain-latency-bound.
__global__ void __attribute__((amdgpu_flat_work_group_size(512, 512)))
__attribute__((amdgpu_waves_per_eu(2, 2)))
k_scan(const float* __restrict__ pf, const float* __restrict__ Wf,
       const float* __restrict__ pb, const float* __restrict__ Wb,
       float* __restrict__ hout) {
    const int dir = blockIdx.x;
    const float* __restrict__ pre = dir ? pb : pf;   // [T][125][4]
    const float* __restrict__ Whh = dir ? Wb : Wf;   // [4][125][125] original
    const int col0 = dir ? 0 : 125;

    __shared__ __align__(32) _Float16 h_lds[2 * 128];   // 2 buffers x 128 halves (125 + pad=0)

    const int t9   = threadIdx.x;
    const int w    = t9 >> 6;        // wave 0..7
    const int lane = t9 & 63;
    const int lane15 = lane & 15;
    const int hi16   = lane >> 4;    // 0..3
    const bool mb0 = (lane & 1) != 0;
    const bool mb1 = (lane & 2) != 0;

    const int uo    = 4 * (lane & 3) + hi16;   // unit-in-wave this lane owns
    const int u_raw = 16 * w + uo;
    const bool valid = (u_raw < LH);
    const int u = valid ? u_raw : (LH - 1);
    const bool writer = ((lane & 12) == 0) && valid;

    // ---- A fragments: 4 M-tiles x 4 K-tiles, row' = 64w + 16m + lane15 (clamped),
    // orig row = (row'&3)*125 + (row'>>2); k = kt*32 + hi16*8 + j.
#define LROW(m) int ro##m; { int rp = 64 * w + 16 * m + lane15; if (rp > 499) rp = 499; \
                             ro##m = (rp & 3) * 125 + (rp >> 2); }
    LROW(0) LROW(1) LROW(2) LROW(3)
#undef LROW
#define LA(m) v8h a##m##0 = packa8(Whh + ro##m * LH, hi16 * 8); \
              v8h a##m##1 = packa8(Whh + ro##m * LH, 32 + hi16 * 8); \
              v8h a##m##2 = packa8(Whh + ro##m * LH, 64 + hi16 * 8); \
              v8h a##m##3 = packa8(Whh + ro##m * LH, 96 + hi16 * 8);
    LA(0) LA(1) LA(2) LA(3)
#undef LA

    for (int q = t9; q < 2 * 128; q += 512) h_lds[q] = (_Float16)0.f;
    float c = 0.f;
    __syncthreads();

    // walking int offsets (one-over prefetch stays inside workspace: pf/pb adjacent)
    const int pstride = dir ? -G4 : G4;
    int poff = (dir ? (T_SEQ - 1) * G4 : 0) + u * 4;
    const int gstride = dir ? -250 : 250;
    int goff = (dir ? (T_SEQ - 1) * 250 : 0) + col0 + u;
    float4 pv4 = *reinterpret_cast<const float4*>(pre + poff);
    poff += pstride;

    const int bbase = hi16 * 8;   // halves offset within a K-tile row

#define SCAN_STEP(CUR, NXT) { \
    float4 pvn = *reinterpret_cast<const float4*>(pre + poff); poff += pstride; \
    const _Float16* hb = &h_lds[(CUR) * 128 + bbase]; \
    v8h bb0 = *reinterpret_cast<const v8h*>(hb); \
    v8h bb1 = *reinterpret_cast<const v8h*>(hb + 32); \
    v8h bb2 = *reinterpret_cast<const v8h*>(hb + 64); \
    v8h bb3 = *reinterpret_cast<const v8h*>(hb + 96); \
    f32x4 z = {0.f, 0.f, 0.f, 0.f}; \
    f32x4 acc0 = __builtin_amdgcn_mfma_f32_16x16x32_f16(a00, bb0, z, 0, 0, 0); \
    acc0 = __builtin_amdgcn_mfma_f32_16x16x32_f16(a01, bb1, acc0, 0, 0, 0); \
    acc0 = __builtin_amdgcn_mfma_f32_16x16x32_f16(a02, bb2, acc0, 0, 0, 0); \
    acc0 = __builtin_amdgcn_mfma_f32_16x16x32_f16(a03, bb3, acc0, 0, 0, 0); \
    f32x4 acc1 = __builtin_amdgcn_mfma_f32_16x16x32_f16(a10, bb0, z, 0, 0, 0); \
    acc1 = __builtin_amdgcn_mfma_f32_16x16x32_f16(a11, bb1, acc1, 0, 0, 0); \
    acc1 = __builtin_amdgcn_mfma_f32_16x16x32_f16(a12, bb2, acc1, 0, 0, 0); \
    acc1 = __builtin_amdgcn_mfma_f32_16x16x32_f16(a13, bb3, acc1, 0, 0, 0); \
    f32x4 acc2 = __builtin_amdgcn_mfma_f32_16x16x32_f16(a20, bb0, z, 0, 0, 0); \
    acc2 = __builtin_amdgcn_mfma_f32_16x16x32_f16(a21, bb1, acc2, 0, 0, 0); \
    acc2 = __builtin_amdgcn_mfma_f32_16x16x32_f16(a22, bb2, acc2, 0, 0, 0); \
    acc2 = __builtin_amdgcn_mfma_f32_16x16x32_f16(a23, bb3, acc2, 0, 0, 0); \
    f32x4 acc3 = __builtin_amdgcn_mfma_f32_16x16x32_f16(a30, bb0, z, 0, 0, 0); \
    acc3 = __builtin_amdgcn_mfma_f32_16x16x32_f16(a31, bb1, acc3, 0, 0, 0); \
    acc3 = __builtin_amdgcn_mfma_f32_16x16x32_f16(a32, bb2, acc3, 0, 0, 0); \
    acc3 = __builtin_amdgcn_mfma_f32_16x16x32_f16(a33, bb3, acc3, 0, 0, 0); \
    float x01_0 = mb0 ? acc1[0] : acc0[0]; float x23_0 = mb0 ? acc3[0] : acc2[0]; \
    float x01_1 = mb0 ? acc1[1] : acc0[1]; float x23_1 = mb0 ? acc3[1] : acc2[1]; \
    float x01_2 = mb0 ? acc1[2] : acc0[2]; float x23_2 = mb0 ? acc3[2] : acc2[2]; \
    float x01_3 = mb0 ? acc1[3] : acc0[3]; float x23_3 = mb0 ? acc3[3] : acc2[3]; \
    float fr0 = mb1 ? x23_0 : x01_0; \
    float fr1 = mb1 ? x23_1 : x01_1; \
    float fr2 = mb1 ? x23_2 : x01_2; \
    float fr3 = mb1 ? x23_3 : x01_3; \
    float gi = fsig(fr0 + pv4.x); \
    float gf = fsig(fr1 + pv4.y); \
    float gg = ftanh(fr2 + pv4.z); \
    float go = fsig(fr3 + pv4.w); \
    c = gf * c + gi * gg; \
    float hnew = go * ftanh(c); \
    if (writer) { \
        h_lds[(NXT) * 128 + u] = (_Float16)hnew; \
        hout[goff] = hnew; \
    } \
    goff += gstride; \
    __syncthreads(); \
    pv4 = pvn; \
}

    for (int s2 = 0; s2 < T_SEQ; s2 += 2) {
        SCAN_STEP(0, 1)
        SCAN_STEP(1, 0)
    }
#undef SCAN_STEP
}

// ---------------- head' = h2 @ FOH + bias ; mod = h2 @ FOM
__global__ void k_headmod(const float* __restrict__ h2,
                          const float* __restrict__ FOH, const float* __restrict__ FOM,
                          const float* __restrict__ bias,
                          float* __restrict__ headp, float* __restrict__ modv) {
    __shared__ float hs[250];
    int t = blockIdx.x, tid = threadIdx.x;   // block 256
    for (int k = tid; k < 250; k += 256) hs[k] = h2[t * 250 + k];
    __syncthreads();
    if (tid < 100) {
        float a = 0.f;
        #pragma unroll 5
        for (int k = 0; k < 250; ++k) a += hs[k] * FOH[k * 100 + tid];
        headp[t * 100 + tid] = a + bias[tid];
    } else if (tid >= 128 && tid < 228) {
        int h = tid - 128;
        float a = 0.f;
        #pragma unroll 5
        for (int k = 0; k < 250; ++k) a += hs[k] * FOM[k * 100 + h];
        modv[t * 100 + h] = a;
    }
}

// ---------------- scores[i][j] = sum_h tanh(head'[i][h] + mod[j][h]) * outW[h]
__global__ void k_score(const float* __restrict__ headp, const float* __restrict__ modv,
                        const float* __restrict__ outw, float* __restrict__ out) {
    __shared__ float hh[16][100];
    __shared__ float mm[16][100];
    __shared__ float ow[100];
    const int bi = blockIdx.y, bj = blockIdx.x;
    const int tx = threadIdx.x, ty = threadIdx.y;   // 16x16
    const int tid = ty * 16 + tx;
    for (int q = tid; q < 1600; q += 256) {
        int r = q / 100, cidx = q % 100;
        hh[r][cidx] = headp[(bi * 16 + r) * 100 + cidx];
        mm[r][cidx] = modv[(bj * 16 + r) * 100 + cidx];
    }
    if (tid < 100) ow[tid] = outw[tid];
    __syncthreads();
    float acc = 0.f;
    #pragma unroll 4
    for (int h = 0; h < 100; ++h) {
        float e = __builtin_amdgcn_exp2f((hh[ty][h] + mm[tx][h]) * -2.8853900817779268f);
        acc += (2.f * __builtin_amdgcn_rcpf(1.f + e) - 1.f) * ow[h];
    }
    out[(bi * 16 + ty) * 1024 + (bj * 16 + tx)] = acc;
}

extern "C" void kernel_launch(void* const* d_in, const int* in_sizes, int n_in,
                              void* d_out, int out_size, void* d_ws, size_t ws_size,
                              hipStream_t stream) {
    const int*   wid    = (const int*)d_in[0];
    const int*   pid    = (const int*)d_in[1];
    const float* W_emb  = (const float*)d_in[2];
    const float* P_emb  = (const float*)d_in[3];
    const float* Wih_f0 = (const float*)d_in[4];
    const float* Whh_f0 = (const float*)d_in[5];
    const float* b_f0   = (const float*)d_in[6];
    const float* Wih_b0 = (const float*)d_in[7];
    const float* Whh_b0 = (const float*)d_in[8];
    const float* b_b0   = (const float*)d_in[9];
    const float* Wih_f1 = (const float*)d_in[10];
    const float* Whh_f1 = (const float*)d_in[11];
    const float* b_f1   = (const float*)d_in[12];
    const float* Wih_b1 = (const float*)d_in[13];
    const float* Whh_b1 = (const float*)d_in[14];
    const float* b_b1   = (const float*)d_in[15];
    const float* FOH    = (const float*)d_in[16];
    const float* FOM    = (const float*)d_in[17];
    const float* hidB   = (const float*)d_in[18];
    const float* outW   = (const float*)d_in[19];
    float* out = (float*)d_out;
    float* ws  = (float*)d_ws;

    float* pf    = ws;                  // 1024*500 (interleaved [t][u][gate])
    float* pb    = pf    + 512000;
    float* h1    = pb    + 512000;      // 1024*250
    float* h2    = h1    + 256000;
    float* headp = h2    + 256000;      // 1024*100
    float* modv  = headp + 102400;

    k_preproj0<<<256, 512, 0, stream>>>(wid, pid, W_emb, P_emb,
                                        Wih_f0, b_f0, Wih_b0, b_b0, pf, pb);
    k_scan<<<2, 512, 0, stream>>>(pf, Whh_f0, pb, Whh_b0, h1);

    k_preproj1<<<256, 512, 0, stream>>>(h1, Wih_f1, b_f1, Wih_b1, b_b1, pf, pb);
    k_scan<<<2, 512, 0, stream>>>(pf, Whh_f1, pb, Whh_b1, h2);

    k_headmod<<<T_SEQ, 256, 0, stream>>>(h2, FOH, FOM, hidB, headp, modv);
    dim3 gs(64, 64), bs(16, 16);
    k_score<<<gs, bs, 0, stream>>>(headp, modv, outW, out);
}